// Round 10
// baseline (198.603 us; speedup 1.0000x reference)
//
#include <hip/hip_runtime.h>

// YOLO loss: preds (B,7,7,30) f32, labels (B,7,7,30) f32 -> scalar f32 (sum/B).
// R11: nt loads (R10's win: partial dropped out of top-5, <57us, total 205->197;
// cache-allocation policy was the 2.6 TB/s wall) + convoy removal. R10 still
// load->drain->compute phases with 2 blocks/CU. R11: each block processes TWO
// 256-cell groups; group g+1's nt loads are issued into registers immediately
// after the post-staging barrier, flying under group g's compute+reduce; the
// ds_write of g+1 happens after g's partial is stored. Partials array, per-
// group shuffle tree (((w0+w1)+w2)+w3 over 64-cell waves), lb0-from-LDS, and
// reduce kernel are bit-identical to R4/R10 -> absmax 0.0.

#define BATCH 16384
#define S 7
#define C 30
#define NCELLS (BATCH * S * S)    // 802816
#define BLOCK 256
#define NC 256                    // cells per group (one partial per group)
#define NGRP (NCELLS / NC)        // 3136 partials (unchanged workspace)
#define NBLK2 (NGRP / 2)          // 1568 blocks, 2 groups each

typedef float f4v __attribute__((ext_vector_type(4)));

__device__ __forceinline__ f4v ntld(const f4v* p) {
    return __builtin_nontemporal_load(p);
}

__device__ __forceinline__ float sq(float v) { return v * v; }

__device__ __forceinline__ float iou_box(float acx, float acy, float aw, float ah,
                                         float bcx, float bcy, float bw, float bh) {
    float ax0 = acx - aw * 0.5f, ax1 = acx + aw * 0.5f;
    float ay0 = acy - ah * 0.5f, ay1 = acy + ah * 0.5f;
    float bx0 = bcx - bw * 0.5f, bx1 = bcx + bw * 0.5f;
    float by0 = bcy - bh * 0.5f, by1 = bcy + bh * 0.5f;
    float iw = fmaxf(fminf(ax1, bx1) - fmaxf(ax0, bx0), 0.0f);
    float ih = fmaxf(fminf(ay1, by1) - fmaxf(ay0, by0), 0.0f);
    float inter = iw * ih;
    float denom = aw * ah + bw * bh - inter + 1e-10f;
    return inter / denom;
}

// issue all 15 nt float4 loads for one group (7+7 full rounds + mixed tail)
__device__ __forceinline__ void stage_regs(const float* __restrict__ preds,
                                           const float* __restrict__ labels,
                                           int base_cell, int tid, int tl,
                                           f4v* rp, f4v* rl) {
    const f4v* gp = reinterpret_cast<const f4v*>(preds  + (size_t)base_cell * C);
    const f4v* gl = reinterpret_cast<const f4v*>(labels + (size_t)base_cell * C);
    #pragma unroll
    for (int k = 0; k < 7; ++k) rl[k] = ntld(gl + tid + k * BLOCK);
    #pragma unroll
    for (int k = 0; k < 7; ++k) rp[k] = ntld(gp + tid + k * BLOCK);
    if (tid < 128) rl[7] = ntld(gl + tl);   // labels f4 [1792,1920)
    else           rp[7] = ntld(gp + tl);   // preds  f4 [1792,1920)
}

__device__ __forceinline__ void write_lds(float* sp, float* sl, int tid, int tl,
                                          const f4v* rp, const f4v* rl) {
    f4v* s4l = reinterpret_cast<f4v*>(sl);
    f4v* s4p = reinterpret_cast<f4v*>(sp);
    #pragma unroll
    for (int k = 0; k < 7; ++k) s4l[tid + k * BLOCK] = rl[k];
    #pragma unroll
    for (int k = 0; k < 7; ++k) s4p[tid + k * BLOCK] = rp[k];
    if (tid < 128) s4l[tl] = rl[7];
    else           s4p[tl] = rp[7];
}

// per-cell loss from LDS (identical math to R4..R10)
__device__ __forceinline__ float cell_loss(const float* __restrict__ sp,
                                           const float* __restrict__ sl,
                                           const float* __restrict__ labels,
                                           int base_cell, int tid) {
    const float* p = sp + tid * C;
    const float* l = sl + tid * C;
    float pv[C], lv[C];
    #pragma unroll
    for (int i = 0; i < C / 2; ++i) {
        float2 tp = *reinterpret_cast<const float2*>(p + 2 * i);
        pv[2 * i] = tp.x; pv[2 * i + 1] = tp.y;
        float2 tl2 = *reinterpret_cast<const float2*>(l + 2 * i);
        lv[2 * i] = tl2.x; lv[2 * i + 1] = tl2.y;
    }

    // transposed label x-coord quirk: labels[b, x, y, 0]
    int cell = base_cell + tid;
    int b    = cell / (S * S);
    int rem  = cell - b * (S * S);
    int y    = rem / S;
    int x    = rem - y * S;
    int pc   = b * (S * S) + x * S + y;
    float lb0;
    if (pc >= base_cell && pc < base_cell + NC) {
        lb0 = sl[(pc - base_cell) * C];
    } else {
        lb0 = labels[(size_t)pc * C];   // rare straddle: cached (non-nt) load
    }

    float iou1 = iou_box(pv[0], pv[1], pv[2], pv[3], lb0, lv[1], lv[2], lv[3]);
    float iou2 = iou_box(pv[5], pv[6], pv[7], pv[8], lb0, lv[1], lv[2], lv[3]);

    float b1 = 5.0f * (sq(pv[0] - lv[0]) + sq(pv[1] - lv[1]))
             + sq(sqrtf(pv[2]) - sqrtf(lv[2])) + sq(sqrtf(pv[3]) - sqrtf(lv[3]))
             + sq(iou1 - pv[4])
             + 0.5f * pv[9] * pv[9];

    float b2 = 5.0f * (sq(pv[5] - lv[5]) + sq(pv[6] - lv[6]))
             + sq(sqrtf(pv[7]) - sqrtf(lv[7])) + sq(sqrtf(pv[8]) - sqrtf(lv[8]))
             + sq(iou2 - pv[9])
             + 0.5f * pv[4] * pv[4];

    float cls = 0.0f;
    #pragma unroll
    for (int c = 10; c < C; ++c) cls += sq(lv[c] - pv[c]);

    float obj_loss   = ((iou1 > iou2) ? b1 : b2) + cls;
    float noobj_loss = 0.5f * (pv[4] * pv[4] + pv[9] * pv[9]);
    return (lv[4] == 1.0f) ? obj_loss : noobj_loss;
}

__global__ __launch_bounds__(BLOCK) void yolo_partial_kernel(
        const float* __restrict__ preds,
        const float* __restrict__ labels,
        float* __restrict__ partials) {
    __shared__ __align__(16) float sp[NC * C];   // 30720 B
    __shared__ __align__(16) float sl[NC * C];   // 30720 B
    __shared__ float wsum[BLOCK / 64];

    const int tid  = threadIdx.x;
    const int lane = tid & 63;
    const int wv   = tid >> 6;
    const int tl   = 1792 + (tid & 127);
    const int g0   = blockIdx.x * 2;
    const int g1   = g0 + 1;

    f4v rl[8], rp[8];

    // ---- group 0: stage -> LDS -> barrier ----
    stage_regs(preds, labels, g0 * NC, tid, tl, rp, rl);
    write_lds(sp, sl, tid, tl, rp, rl);
    __syncthreads();

    // ---- issue group 1's nt loads NOW: in flight under g0 compute+reduce ----
    stage_regs(preds, labels, g1 * NC, tid, tl, rp, rl);

    // ---- group 0 compute + reduction (tree identical to R4) ----
    float loss = cell_loss(sp, sl, labels, g0 * NC, tid);
    #pragma unroll
    for (int off = 32; off > 0; off >>= 1)
        loss += __shfl_down(loss, off, 64);
    if (lane == 0) wsum[wv] = loss;
    __syncthreads();                       // also: all LDS reads of g0 retired
    if (tid == 0)
        partials[g0] = wsum[0] + wsum[1] + wsum[2] + wsum[3];

    // ---- land group 1 in LDS (loads had g0's compute to return) ----
    write_lds(sp, sl, tid, tl, rp, rl);
    __syncthreads();

    // ---- group 1 compute + reduction ----
    loss = cell_loss(sp, sl, labels, g1 * NC, tid);
    #pragma unroll
    for (int off = 32; off > 0; off >>= 1)
        loss += __shfl_down(loss, off, 64);
    if (lane == 0) wsum[wv] = loss;
    __syncthreads();
    if (tid == 0)
        partials[g1] = wsum[0] + wsum[1] + wsum[2] + wsum[3];
}

__global__ __launch_bounds__(BLOCK) void yolo_reduce_kernel(
        const float* __restrict__ partials,
        float* __restrict__ out) {
    const int tid = threadIdx.x;
    float s = 0.0f;
    for (int i = tid; i < NGRP; i += BLOCK) s += partials[i];

    #pragma unroll
    for (int off = 32; off > 0; off >>= 1)
        s += __shfl_down(s, off, 64);

    __shared__ float wsum[BLOCK / 64];
    int lane = tid & 63;
    int wv   = tid >> 6;
    if (lane == 0) wsum[wv] = s;
    __syncthreads();
    if (tid == 0) {
        out[0] = (wsum[0] + wsum[1] + wsum[2] + wsum[3]) * (1.0f / (float)BATCH);
    }
}

extern "C" void kernel_launch(void* const* d_in, const int* in_sizes, int n_in,
                              void* d_out, int out_size, void* d_ws, size_t ws_size,
                              hipStream_t stream) {
    const float* preds  = (const float*)d_in[0];
    const float* labels = (const float*)d_in[1];
    float* out = (float*)d_out;
    float* partials = (float*)d_ws;   // NGRP floats = 12.25 KB (unchanged)

    yolo_partial_kernel<<<NBLK2, BLOCK, 0, stream>>>(preds, labels, partials);
    yolo_reduce_kernel<<<1, BLOCK, 0, stream>>>(partials, out);
}